// Round 1
// baseline (7642.909 us; speedup 1.0000x reference)
//
#include <hip/hip_runtime.h>
#include <math.h>

#define BB 8
#define NN 2048
#define HID 768
#define NHEADS 4
#define ALPHA 0.2f
#define NEGV -9e15f

// ---------------------------------------------------------------------------
// Embedding lookup: x[b,n,:] = table[node_feats[b,n],:]
// ---------------------------------------------------------------------------
__global__ __launch_bounds__(256) void embed_kernel(
    const int* __restrict__ nf, const float* __restrict__ table,
    float* __restrict__ x) {
  long idx = (long)blockIdx.x * 256 + threadIdx.x;  // over B*N*HID
  int col  = (int)(idx % HID);
  long node = idx / HID;
  x[idx] = table[(long)nf[node] * HID + col];
}

// ---------------------------------------------------------------------------
// Generic batched fp32 GEMM: C[b] = A[b] @ Bw[b], optional ELU epilogue.
// Tile 64x64, BK=16, 256 threads, 4x4 per thread. All dims divisible:
// M % 64 == 0, Nn % 64 == 0, K % 16 == 0 (holds for all calls here).
// ---------------------------------------------------------------------------
__global__ __launch_bounds__(256) void gemm_kernel(
    const float* __restrict__ A, const float* __restrict__ Bw,
    float* __restrict__ C,
    int M, int Nn, int K, int lda, int ldb, int ldc,
    long sA, long sB, long sC, int elu) {
  const int b = blockIdx.z;
  A += (long)b * sA;
  Bw += (long)b * sB;
  C += (long)b * sC;

  const int m0 = blockIdx.y * 64;
  const int n0 = blockIdx.x * 64;

  __shared__ float As[64][17];  // [m][k]
  __shared__ float Bs[16][68];  // [k][n]

  const int tid = threadIdx.x;
  const int tx = tid & 15;   // 0..15 -> col group
  const int ty = tid >> 4;   // 0..15 -> row group

  float acc[4][4];
#pragma unroll
  for (int i = 0; i < 4; ++i)
#pragma unroll
    for (int j = 0; j < 4; ++j) acc[i][j] = 0.f;

  for (int k0 = 0; k0 < K; k0 += 16) {
    // stage A tile 64x16
#pragma unroll
    for (int it = 0; it < 4; ++it) {
      int idx = tid + it * 256;
      int r = idx >> 4, c = idx & 15;
      As[r][c] = A[(long)(m0 + r) * lda + (k0 + c)];
    }
    // stage B tile 16x64
#pragma unroll
    for (int it = 0; it < 4; ++it) {
      int idx = tid + it * 256;
      int r = idx >> 6, c = idx & 63;
      Bs[r][c] = Bw[(long)(k0 + r) * ldb + (n0 + c)];
    }
    __syncthreads();
#pragma unroll
    for (int kk = 0; kk < 16; ++kk) {
      float av[4], bv[4];
#pragma unroll
      for (int i = 0; i < 4; ++i) av[i] = As[ty + i * 16][kk];
#pragma unroll
      for (int j = 0; j < 4; ++j) bv[j] = Bs[kk][tx + j * 16];
#pragma unroll
      for (int i = 0; i < 4; ++i)
#pragma unroll
        for (int j = 0; j < 4; ++j) acc[i][j] = fmaf(av[i], bv[j], acc[i][j]);
    }
    __syncthreads();
  }

#pragma unroll
  for (int i = 0; i < 4; ++i) {
    int rm = m0 + ty + i * 16;
#pragma unroll
    for (int j = 0; j < 4; ++j) {
      int cn = n0 + tx + j * 16;
      float v = acc[i][j];
      if (elu) v = v > 0.f ? v : (expf(v) - 1.f);
      C[(long)rm * ldc + cn] = v;
    }
  }
}

// ---------------------------------------------------------------------------
// Wh1[row] = Wh[row,:] . a[0:HID], Wh2[row] = Wh[row,:] . a[HID:2*HID]
// One block (256 thr) per row.
// ---------------------------------------------------------------------------
__global__ __launch_bounds__(256) void attvec_kernel(
    const float* __restrict__ Wh, const float* __restrict__ a,
    float* __restrict__ Wh1, float* __restrict__ Wh2) {
  int row = blockIdx.x;
  const float* w = Wh + (long)row * HID;
  float s1 = 0.f, s2 = 0.f;
  for (int c = threadIdx.x; c < HID; c += 256) {
    float v = w[c];
    s1 += v * a[c];
    s2 += v * a[HID + c];
  }
  __shared__ float r1[256], r2[256];
  r1[threadIdx.x] = s1;
  r2[threadIdx.x] = s2;
  __syncthreads();
  for (int s = 128; s > 0; s >>= 1) {
    if (threadIdx.x < s) {
      r1[threadIdx.x] += r1[threadIdx.x + s];
      r2[threadIdx.x] += r2[threadIdx.x + s];
    }
    __syncthreads();
  }
  if (threadIdx.x == 0) {
    Wh1[row] = r1[0];
    Wh2[row] = r2[0];
  }
}

// ---------------------------------------------------------------------------
// Attention row softmax: e_j = lrelu(Wh1[i] + Wh2[j]); mask by adj; softmax.
// One block per (b,i) row; row of 2048 lives in LDS.
// ---------------------------------------------------------------------------
__global__ __launch_bounds__(256) void attn_softmax_kernel(
    const float* __restrict__ Wh1, const float* __restrict__ Wh2,
    const int* __restrict__ adj, float* __restrict__ att) {
  int row = blockIdx.x;  // 0 .. B*N-1
  int b = row / NN;
  long rowbase = (long)row * NN;
  const int* adjrow = adj + rowbase;
  const float* wh2b = Wh2 + (long)b * NN;

  __shared__ float e[NN];
  __shared__ float red[256];

  float wh1 = Wh1[row];
  float lmax = -INFINITY;
  for (int j = threadIdx.x; j < NN; j += 256) {
    float v = wh1 + wh2b[j];
    v = v > 0.f ? v : ALPHA * v;
    v = adjrow[j] > 0 ? v : NEGV;
    e[j] = v;
    lmax = fmaxf(lmax, v);
  }
  red[threadIdx.x] = lmax;
  __syncthreads();
  for (int s = 128; s > 0; s >>= 1) {
    if (threadIdx.x < s)
      red[threadIdx.x] = fmaxf(red[threadIdx.x], red[threadIdx.x + s]);
    __syncthreads();
  }
  float m = red[0];
  __syncthreads();

  float lsum = 0.f;
  for (int j = threadIdx.x; j < NN; j += 256) {
    float p = expf(e[j] - m);
    e[j] = p;
    lsum += p;
  }
  red[threadIdx.x] = lsum;
  __syncthreads();
  for (int s = 128; s > 0; s >>= 1) {
    if (threadIdx.x < s) red[threadIdx.x] += red[threadIdx.x + s];
    __syncthreads();
  }
  float inv = 1.f / red[0];
  for (int j = threadIdx.x; j < NN; j += 256) att[rowbase + j] = e[j] * inv;
}

// ---------------------------------------------------------------------------
// Final pooling: out[b,c] = (1/N) * sum_n elu(h2[b,n,c])
// ---------------------------------------------------------------------------
__global__ __launch_bounds__(256) void zero_out_kernel(float* __restrict__ out) {
  int i = blockIdx.x * 256 + threadIdx.x;
  if (i < BB * HID) out[i] = 0.f;
}

__global__ __launch_bounds__(256) void pool_kernel(
    const float* __restrict__ h2, float* __restrict__ out) {
  int b = blockIdx.y;
  int z = blockIdx.z;  // n-chunk of 64
  int c = blockIdx.x * 256 + threadIdx.x;
  float s = 0.f;
  int n0 = z * 64;
  for (int n = n0; n < n0 + 64; ++n) {
    float v = h2[((long)b * NN + n) * HID + c];
    v = v > 0.f ? v : (expf(v) - 1.f);
    s += v;
  }
  atomicAdd(out + b * HID + c, s * (1.0f / NN));
}

// ---------------------------------------------------------------------------
extern "C" void kernel_launch(void* const* d_in, const int* in_sizes, int n_in,
                              void* d_out, int out_size, void* d_ws,
                              size_t ws_size, hipStream_t stream) {
  const int* node_feats = (const int*)d_in[0];        // (B,N)
  const int* adjs = (const int*)d_in[1];              // (B,N,N)
  const float* embed_table = (const float*)d_in[2];   // (15,HID)
  const float* W_heads = (const float*)d_in[3];       // (4,HID,HID)
  const float* a_heads = (const float*)d_in[4];       // (4,2*HID,1)
  const float* W_out = (const float*)d_in[5];         // (4*HID,HID)
  const float* a_out = (const float*)d_in[6];         // (2*HID,1)
  float* out = (float*)d_out;                         // (B,HID)

  // workspace layout (floats)
  const size_t n_x = (size_t)BB * NN * HID;            // 12,582,912
  const size_t n_hcat = (size_t)BB * NN * NHEADS * HID;// 50,331,648
  const size_t n_att = (size_t)BB * NN * NN;           // 33,554,432
  const size_t need = (n_x + n_hcat + n_x + n_att + 2 * (size_t)BB * NN) * 4;
  if (ws_size < need) return;  // deterministic failure if ws too small

  float* ws = (float*)d_ws;
  float* x = ws;
  float* hcat = x + n_x;
  float* Wh = hcat + n_hcat;
  float* att = Wh + n_x;
  float* Wh1 = att + n_att;
  float* Wh2 = Wh1 + (size_t)BB * NN;

  const long M = (long)BB * NN;  // 16384

  // 1) embedding
  embed_kernel<<<(BB * NN * HID) / 256, 256, 0, stream>>>(node_feats,
                                                          embed_table, x);

  // 2) per-head GAT layer
  for (int h = 0; h < NHEADS; ++h) {
    // Wh = x @ W_h   (16384 x 768 x 768)
    gemm_kernel<<<dim3(HID / 64, M / 64, 1), 256, 0, stream>>>(
        x, W_heads + (long)h * HID * HID, Wh, (int)M, HID, HID, HID, HID, HID,
        0, 0, 0, 0);
    // Wh1/Wh2
    attvec_kernel<<<(int)M, 256, 0, stream>>>(Wh, a_heads + (long)h * 2 * HID,
                                              Wh1, Wh2);
    // masked softmax rows
    attn_softmax_kernel<<<(int)M, 256, 0, stream>>>(Wh1, Wh2, adjs, att);
    // hcat[:, :, h*HID : (h+1)*HID] = elu(att @ Wh)   (batched)
    gemm_kernel<<<dim3(HID / 64, NN / 64, BB), 256, 0, stream>>>(
        att, Wh, hcat + (long)h * HID, NN, HID, NN, NN, HID, NHEADS * HID,
        (long)NN * NN, (long)NN * HID, (long)NN * NHEADS * HID, 1);
  }

  // 3) output GAT layer
  // Who = hcat @ W_out   (16384 x 3072 x 768), store into Wh buffer
  gemm_kernel<<<dim3(HID / 64, M / 64, 1), 256, 0, stream>>>(
      hcat, W_out, Wh, (int)M, HID, NHEADS * HID, NHEADS * HID, HID, HID, 0, 0,
      0, 0);
  attvec_kernel<<<(int)M, 256, 0, stream>>>(Wh, a_out, Wh1, Wh2);
  attn_softmax_kernel<<<(int)M, 256, 0, stream>>>(Wh1, Wh2, adjs, att);
  // h2 = att @ Who  -> reuse x buffer
  gemm_kernel<<<dim3(HID / 64, NN / 64, BB), 256, 0, stream>>>(
      att, Wh, x, NN, HID, NN, NN, HID, HID, (long)NN * NN, (long)NN * HID,
      (long)NN * HID, 0);

  // 4) mean-pool with ELU
  zero_out_kernel<<<(BB * HID + 255) / 256, 256, 0, stream>>>(out);
  pool_kernel<<<dim3(HID / 256, BB, NN / 64), 256, 0, stream>>>(x, out);
}

// Round 2
// 1337.023 us; speedup vs baseline: 5.7164x; 5.7164x over previous
//
#include <hip/hip_runtime.h>
#include <math.h>

#define BB 8
#define NN 2048
#define HID 768
#define NHEADS 4
#define ALPHA 0.2f
#define NEGV -9e15f

using short4v = __attribute__((ext_vector_type(4))) short;
using short8v = __attribute__((ext_vector_type(8))) short;
using f32x4 = __attribute__((ext_vector_type(4))) float;

__device__ __forceinline__ short f2bf(float f) {
  union { float f; unsigned u; } x;
  x.f = f;
  unsigned r = x.u + 0x7fffu + ((x.u >> 16) & 1u);
  return (short)(r >> 16);
}

__device__ __forceinline__ void cp16(const void* g, void* l) {
  __builtin_amdgcn_global_load_lds(
      (const __attribute__((address_space(1))) unsigned int*)g,
      (__attribute__((address_space(3))) unsigned int*)l, 16, 0, 0);
}

// ---------------------------------------------------------------------------
// Embedding lookup -> bf16: x[b,n,:] = bf16(table[node_feats[b,n],:])
// ---------------------------------------------------------------------------
__global__ __launch_bounds__(256) void embed_kernel(
    const int* __restrict__ nf, const float* __restrict__ table,
    short* __restrict__ x) {
  long idx = (long)blockIdx.x * 256 + threadIdx.x;  // over B*N*HID
  int col = (int)(idx % HID);
  long node = idx / HID;
  x[idx] = f2bf(table[(long)nf[node] * HID + col]);
}

// ---------------------------------------------------------------------------
// fp32 -> bf16 transpose: Wt[n*K + k] = bf16(W[k*N + n]), per blockIdx.z mat
// ---------------------------------------------------------------------------
__global__ __launch_bounds__(256) void transpose_bf16(
    const float* __restrict__ W, short* __restrict__ Wt, int K, int N,
    long sIn, long sOut) {
  __shared__ float t[32][33];
  W += (long)blockIdx.z * sIn;
  Wt += (long)blockIdx.z * sOut;
  int k0 = blockIdx.x * 32, n0 = blockIdx.y * 32;
  int tx = threadIdx.x & 31, ty = threadIdx.x >> 5;  // ty 0..7
#pragma unroll
  for (int i = 0; i < 32; i += 8) t[ty + i][tx] = W[(long)(k0 + ty + i) * N + n0 + tx];
  __syncthreads();
#pragma unroll
  for (int i = 0; i < 32; i += 8)
    Wt[(long)(n0 + ty + i) * K + k0 + tx] = f2bf(t[tx][ty + i]);
}

// ---------------------------------------------------------------------------
// bf16 MFMA GEMM: C = A(bf16, MxK row-major) @ B'(bf16, [n][k] row-major)^T
// 128x128 tile, BK=32, 256 thr (4 waves, each 64x64 via 4x4 16x16x32 MFMA).
// global_load_lds 16B staging with XOR chunk swizzle (global-side permute so
// LDS dest stays lane-contiguous; read-side 2-way bank alias = free).
// mode 0: C fp32 (ldc) + Ct bf16 transposed per-2048-row-batch [bb][n][m]
// mode 1: Cb bf16 (ldcb) with ELU
// mode 2: C fp32 only
// ---------------------------------------------------------------------------
__global__ __launch_bounds__(256) void mfma_gemm(
    const short* __restrict__ A, const short* __restrict__ B,
    int K, int lda, int ldb, long sA, long sB,
    float* __restrict__ C, int ldc, long sC,
    short* __restrict__ Cb, int ldcb, long sCb,
    short* __restrict__ Ct, int mode) {
  __shared__ short As[128 * 32];
  __shared__ short Bs[128 * 32];

  const int z = blockIdx.z;
  A += (long)z * sA;
  B += (long)z * sB;

  const int tid = threadIdx.x;
  const int m0 = blockIdx.y * 128;
  const int n0 = blockIdx.x * 128;

  const int lane = tid & 63;
  const int wid = tid >> 6;
  const int wm = (wid & 1) * 64;
  const int wn = (wid >> 1) * 64;
  const int l15 = lane & 15;
  const int quad = lane >> 4;
  const int cp = quad ^ ((l15 >> 1) & 3);  // swizzled chunk slot for frag read

  f32x4 acc[4][4];
#pragma unroll
  for (int i = 0; i < 4; ++i)
#pragma unroll
    for (int j = 0; j < 4; ++j) acc[i][j] = (f32x4){0.f, 0.f, 0.f, 0.f};

  for (int k0 = 0; k0 < K; k0 += 32) {
    // stage A: 128 rows x 32 bf16 (64B/row as 4 x 16B chunks, slot p holds
    // global chunk p ^ ((r>>1)&3))
#pragma unroll
    for (int it = 0; it < 2; ++it) {
      int lin = it * 256 + tid;
      int r = lin >> 2;
      int p = lin & 3;
      int kc = p ^ ((r >> 1) & 3);
      cp16(A + (long)(m0 + r) * lda + k0 + kc * 8, &As[lin * 8]);
    }
#pragma unroll
    for (int it = 0; it < 2; ++it) {
      int lin = it * 256 + tid;
      int r = lin >> 2;
      int p = lin & 3;
      int kc = p ^ ((r >> 1) & 3);
      cp16(B + (long)(n0 + r) * ldb + k0 + kc * 8, &Bs[lin * 8]);
    }
    __syncthreads();

    short8v af[4], bfr[4];
#pragma unroll
    for (int i = 0; i < 4; ++i)
      af[i] = *(const short8v*)(As + (wm + i * 16 + l15) * 32 + cp * 8);
#pragma unroll
    for (int j = 0; j < 4; ++j)
      bfr[j] = *(const short8v*)(Bs + (wn + j * 16 + l15) * 32 + cp * 8);
#pragma unroll
    for (int i = 0; i < 4; ++i)
#pragma unroll
      for (int j = 0; j < 4; ++j)
        acc[i][j] = __builtin_amdgcn_mfma_f32_16x16x32_bf16(af[i], bfr[j],
                                                            acc[i][j], 0, 0, 0);
    __syncthreads();
  }

  // epilogue: C/D layout col=lane&15, row=quad*4+reg
  if (mode == 1) {
    Cb += (long)z * sCb;
#pragma unroll
    for (int i = 0; i < 4; ++i) {
      int rb = m0 + wm + i * 16 + quad * 4;
#pragma unroll
      for (int j = 0; j < 4; ++j) {
        int col = n0 + wn + j * 16 + l15;
#pragma unroll
        for (int reg = 0; reg < 4; ++reg) {
          float v = acc[i][j][reg];
          v = v > 0.f ? v : (expf(v) - 1.f);
          Cb[(long)(rb + reg) * ldcb + col] = f2bf(v);
        }
      }
    }
  } else {
    C += (long)z * sC;
#pragma unroll
    for (int i = 0; i < 4; ++i) {
      int rb = m0 + wm + i * 16 + quad * 4;
#pragma unroll
      for (int j = 0; j < 4; ++j) {
        int col = n0 + wn + j * 16 + l15;
#pragma unroll
        for (int reg = 0; reg < 4; ++reg) C[(long)(rb + reg) * ldc + col] = acc[i][j][reg];
        if (mode == 0) {
          int bb = rb >> 11;       // 2048 rows per batch
          int ml = rb & 2047;
          short4v pk;
#pragma unroll
          for (int reg = 0; reg < 4; ++reg) pk[reg] = f2bf(acc[i][j][reg]);
          *(short4v*)(Ct + ((long)bb * HID + col) * NN + ml) = pk;
        }
      }
    }
  }
}

// ---------------------------------------------------------------------------
// Wh1[row] = Wh[row,:] . a[0:HID], Wh2[row] = Wh[row,:] . a[HID:2*HID]
// ---------------------------------------------------------------------------
__global__ __launch_bounds__(256) void attvec_kernel(
    const float* __restrict__ Wh, const float* __restrict__ a,
    float* __restrict__ Wh1, float* __restrict__ Wh2) {
  int row = blockIdx.x;
  const float* w = Wh + (long)row * HID;
  float s1 = 0.f, s2 = 0.f;
  for (int c = threadIdx.x; c < HID; c += 256) {
    float v = w[c];
    s1 += v * a[c];
    s2 += v * a[HID + c];
  }
  __shared__ float r1[256], r2[256];
  r1[threadIdx.x] = s1;
  r2[threadIdx.x] = s2;
  __syncthreads();
  for (int s = 128; s > 0; s >>= 1) {
    if (threadIdx.x < s) {
      r1[threadIdx.x] += r1[threadIdx.x + s];
      r2[threadIdx.x] += r2[threadIdx.x + s];
    }
    __syncthreads();
  }
  if (threadIdx.x == 0) {
    Wh1[row] = r1[0];
    Wh2[row] = r2[0];
  }
}

// ---------------------------------------------------------------------------
// Row softmax with LeakyReLU + adjacency mask; writes bf16 att.
// ---------------------------------------------------------------------------
__global__ __launch_bounds__(256) void attn_softmax_kernel(
    const float* __restrict__ Wh1, const float* __restrict__ Wh2,
    const int* __restrict__ adj, short* __restrict__ att) {
  int row = blockIdx.x;  // 0 .. B*N-1
  int b = row / NN;
  long rowbase = (long)row * NN;
  const int* adjrow = adj + rowbase;
  const float* wh2b = Wh2 + (long)b * NN;

  __shared__ float e[NN];
  __shared__ float red[256];

  float wh1 = Wh1[row];
  float lmax = -INFINITY;
  for (int j = threadIdx.x; j < NN; j += 256) {
    float v = wh1 + wh2b[j];
    v = v > 0.f ? v : ALPHA * v;
    v = adjrow[j] > 0 ? v : NEGV;
    e[j] = v;
    lmax = fmaxf(lmax, v);
  }
  red[threadIdx.x] = lmax;
  __syncthreads();
  for (int s = 128; s > 0; s >>= 1) {
    if (threadIdx.x < s)
      red[threadIdx.x] = fmaxf(red[threadIdx.x], red[threadIdx.x + s]);
    __syncthreads();
  }
  float m = red[0];
  __syncthreads();

  float lsum = 0.f;
  for (int j = threadIdx.x; j < NN; j += 256) {
    float p = expf(e[j] - m);
    e[j] = p;
    lsum += p;
  }
  red[threadIdx.x] = lsum;
  __syncthreads();
  for (int s = 128; s > 0; s >>= 1) {
    if (threadIdx.x < s) red[threadIdx.x] += red[threadIdx.x + s];
    __syncthreads();
  }
  float inv = 1.f / red[0];
  for (int j = threadIdx.x; j < NN; j += 256) att[rowbase + j] = f2bf(e[j] * inv);
}

// ---------------------------------------------------------------------------
// Final pooling: out[b,c] = (1/N) * sum_n elu(h2[b,n,c])
// ---------------------------------------------------------------------------
__global__ __launch_bounds__(256) void zero_out_kernel(float* __restrict__ out) {
  int i = blockIdx.x * 256 + threadIdx.x;
  if (i < BB * HID) out[i] = 0.f;
}

__global__ __launch_bounds__(256) void pool_kernel(
    const float* __restrict__ h2, float* __restrict__ out) {
  int b = blockIdx.y;
  int z = blockIdx.z;  // n-chunk of 64
  int c = blockIdx.x * 256 + threadIdx.x;
  float s = 0.f;
  int n0 = z * 64;
  for (int n = n0; n < n0 + 64; ++n) {
    float v = h2[((long)b * NN + n) * HID + c];
    v = v > 0.f ? v : (expf(v) - 1.f);
    s += v;
  }
  atomicAdd(out + b * HID + c, s * (1.0f / NN));
}

// ---------------------------------------------------------------------------
extern "C" void kernel_launch(void* const* d_in, const int* in_sizes, int n_in,
                              void* d_out, int out_size, void* d_ws,
                              size_t ws_size, hipStream_t stream) {
  const int* node_feats = (const int*)d_in[0];       // (B,N)
  const int* adjs = (const int*)d_in[1];             // (B,N,N)
  const float* embed_table = (const float*)d_in[2];  // (15,HID)
  const float* W_heads = (const float*)d_in[3];      // (4,HID,HID)
  const float* a_heads = (const float*)d_in[4];      // (4,2*HID,1)
  const float* W_out = (const float*)d_in[5];        // (4*HID,HID)
  const float* a_out = (const float*)d_in[6];        // (2*HID,1)
  float* out = (float*)d_out;                        // (B,HID)

  const long M = (long)BB * NN;  // 16384

  // workspace layout
  char* p = (char*)d_ws;
  short* x_bf = (short*)p;  p += (size_t)M * HID * 2;                  // 25 MB
  short* Wt_h = (short*)p;  p += (size_t)NHEADS * HID * HID * 2;       // 4.7 MB
  short* Wt_o = (short*)p;  p += (size_t)HID * (NHEADS * HID) * 2;     // 4.7 MB
  float* Wh = (float*)p;    p += (size_t)M * HID * 4;                  // 50 MB
  short* Wh_t = (short*)p;  p += (size_t)BB * HID * NN * 2;            // 25 MB
  short* att = (short*)p;   p += (size_t)BB * NN * NN * 2;             // 67 MB
  short* hcat = (short*)p;  p += (size_t)M * NHEADS * HID * 2;         // 100 MB
  float* h2 = (float*)p;    p += (size_t)M * HID * 4;                  // 50 MB
  float* Wh1 = (float*)p;   p += (size_t)M * 4;
  float* Wh2 = (float*)p;   p += (size_t)M * 4;
  if ((size_t)(p - (char*)d_ws) > ws_size) return;

  // 0) weight transposes (bf16, [n][k])
  transpose_bf16<<<dim3(HID / 32, HID / 32, NHEADS), 256, 0, stream>>>(
      W_heads, Wt_h, HID, HID, (long)HID * HID, (long)HID * HID);
  transpose_bf16<<<dim3((NHEADS * HID) / 32, HID / 32, 1), 256, 0, stream>>>(
      W_out, Wt_o, NHEADS * HID, HID, 0, 0);

  // 1) embedding -> bf16
  embed_kernel<<<(int)(M * HID / 256), 256, 0, stream>>>(node_feats,
                                                         embed_table, x_bf);

  // 2) per-head GAT layer
  for (int h = 0; h < NHEADS; ++h) {
    // Wh(fp32) + Wh_t(bf16,[b][n][m]) = x @ W_h
    mfma_gemm<<<dim3(HID / 128, M / 128, 1), 256, 0, stream>>>(
        x_bf, Wt_h + (long)h * HID * HID, HID, HID, HID, 0, 0,
        Wh, HID, 0, nullptr, 0, 0, Wh_t, 0);
    attvec_kernel<<<(int)M, 256, 0, stream>>>(Wh, a_heads + (long)h * 2 * HID,
                                              Wh1, Wh2);
    attn_softmax_kernel<<<(int)M, 256, 0, stream>>>(Wh1, Wh2, adjs, att);
    // hcat[:, h*HID:(h+1)*HID] = elu(att @ Wh), batched over B
    mfma_gemm<<<dim3(HID / 128, NN / 128, BB), 256, 0, stream>>>(
        att, Wh_t, NN, NN, NN, (long)NN * NN, (long)HID * NN,
        nullptr, 0, 0, hcat + (long)h * HID, NHEADS * HID, (long)NN * NHEADS * HID,
        nullptr, 1);
  }

  // 3) output GAT layer
  mfma_gemm<<<dim3(HID / 128, M / 128, 1), 256, 0, stream>>>(
      hcat, Wt_o, NHEADS * HID, NHEADS * HID, NHEADS * HID, 0, 0,
      Wh, HID, 0, nullptr, 0, 0, Wh_t, 0);
  attvec_kernel<<<(int)M, 256, 0, stream>>>(Wh, a_out, Wh1, Wh2);
  attn_softmax_kernel<<<(int)M, 256, 0, stream>>>(Wh1, Wh2, adjs, att);
  mfma_gemm<<<dim3(HID / 128, NN / 128, BB), 256, 0, stream>>>(
      att, Wh_t, NN, NN, NN, (long)NN * NN, (long)HID * NN,
      h2, HID, (long)NN * HID, nullptr, 0, 0, nullptr, 2);

  // 4) mean-pool with ELU
  zero_out_kernel<<<(BB * HID + 255) / 256, 256, 0, stream>>>(out);
  pool_kernel<<<dim3(HID / 256, BB, NN / 64), 256, 0, stream>>>(h2, out);
}

// Round 3
// 1039.698 us; speedup vs baseline: 7.3511x; 1.2860x over previous
//
#include <hip/hip_runtime.h>
#include <math.h>

#define BB 8
#define NN 2048
#define HID 768
#define NHEADS 4
#define ALPHA 0.2f
#define NEGV -9e15f

using short4v = __attribute__((ext_vector_type(4))) short;
using short8v = __attribute__((ext_vector_type(8))) short;
using f32x4 = __attribute__((ext_vector_type(4))) float;

__device__ __forceinline__ short f2bf(float f) {
  union { float f; unsigned u; } x;
  x.f = f;
  unsigned r = x.u + 0x7fffu + ((x.u >> 16) & 1u);
  return (short)(r >> 16);
}

__device__ __forceinline__ void cp16(const void* g, void* l) {
  __builtin_amdgcn_global_load_lds(
      (const __attribute__((address_space(1))) unsigned int*)g,
      (__attribute__((address_space(3))) unsigned int*)l, 16, 0, 0);
}

// ---------------------------------------------------------------------------
// Embedding lookup -> bf16
// ---------------------------------------------------------------------------
__global__ __launch_bounds__(256) void embed_kernel(
    const int* __restrict__ nf, const float* __restrict__ table,
    short* __restrict__ x) {
  long idx = (long)blockIdx.x * 256 + threadIdx.x;  // over B*N*HID
  int col = (int)(idx % HID);
  long node = idx / HID;
  x[idx] = f2bf(table[(long)nf[node] * HID + col]);
}

// ---------------------------------------------------------------------------
// Adjacency bit-pack: 64 consecutive adj ints -> one u64 via ballot
// ---------------------------------------------------------------------------
__global__ __launch_bounds__(256) void pack_adj_kernel(
    const int* __restrict__ adj, unsigned long long* __restrict__ packed) {
  long idx = (long)blockIdx.x * 256 + threadIdx.x;  // over B*N*N
  unsigned long long m = __ballot(adj[idx] > 0);
  if ((threadIdx.x & 63) == 0) packed[idx >> 6] = m;
}

// ---------------------------------------------------------------------------
// fp32 -> bf16 transpose (weights)
// ---------------------------------------------------------------------------
__global__ __launch_bounds__(256) void transpose_bf16(
    const float* __restrict__ W, short* __restrict__ Wt, int K, int N,
    long sIn, long sOut) {
  __shared__ float t[32][33];
  W += (long)blockIdx.z * sIn;
  Wt += (long)blockIdx.z * sOut;
  int k0 = blockIdx.x * 32, n0 = blockIdx.y * 32;
  int tx = threadIdx.x & 31, ty = threadIdx.x >> 5;
#pragma unroll
  for (int i = 0; i < 32; i += 8) t[ty + i][tx] = W[(long)(k0 + ty + i) * N + n0 + tx];
  __syncthreads();
#pragma unroll
  for (int i = 0; i < 32; i += 8)
    Wt[(long)(n0 + ty + i) * K + k0 + tx] = f2bf(t[tx][ty + i]);
}

__global__ __launch_bounds__(256) void zero_kernel(float* __restrict__ p, int n) {
  int i = blockIdx.x * 256 + threadIdx.x;
  if (i < n) p[i] = 0.f;
}

// ---------------------------------------------------------------------------
// bf16 MFMA GEMM: C = A(MxK rm) @ B'([n][k] rm)^T, 128x128 tile, BK=32.
// XCD-aware swizzle: lin%8 = XCD gets contiguous work range, x fastest.
// mode 0: Ct bf16 transposed [bb][col][row] + fused a-dot -> atomic Wh1/Wh2
// mode 1: Cb bf16 with ELU
// mode 2: C fp32
// ---------------------------------------------------------------------------
__global__ __launch_bounds__(256) void mfma_gemm(
    const short* __restrict__ A, const short* __restrict__ B,
    int K, int lda, int ldb, long sA, long sB,
    float* __restrict__ C, int ldc, long sC,
    short* __restrict__ Cb, int ldcb, long sCb,
    short* __restrict__ Ct,
    const float* __restrict__ a_vec, float* __restrict__ Wh1g,
    float* __restrict__ Wh2g, int mode) {
  __shared__ short As[128 * 32];
  __shared__ short Bs[128 * 32];

  // --- swizzle: cluster same-A-strip blocks on one XCD ---
  const int gx = gridDim.x, gy = gridDim.y;
  int lin = blockIdx.x + gx * (blockIdx.y + gy * blockIdx.z);
  const int per = (gx * gy * gridDim.z) >> 3;  // grids are %8==0 by design
  int work = (lin & 7) * per + (lin >> 3);
  const int bx = work % gx;
  int tmp = work / gx;
  const int by = tmp % gy;
  const int z = tmp / gy;

  A += (long)z * sA;
  B += (long)z * sB;

  const int tid = threadIdx.x;
  const int m0 = by * 128;
  const int n0 = bx * 128;

  const int lane = tid & 63;
  const int wid = tid >> 6;
  const int wm = (wid & 1) * 64;
  const int wn = (wid >> 1) * 64;
  const int l15 = lane & 15;
  const int quad = lane >> 4;
  const int cp = quad ^ ((l15 >> 1) & 3);

  f32x4 acc[4][4];
#pragma unroll
  for (int i = 0; i < 4; ++i)
#pragma unroll
    for (int j = 0; j < 4; ++j) acc[i][j] = (f32x4){0.f, 0.f, 0.f, 0.f};

  for (int k0 = 0; k0 < K; k0 += 32) {
#pragma unroll
    for (int it = 0; it < 2; ++it) {
      int lin2 = it * 256 + tid;
      int r = lin2 >> 2;
      int p = lin2 & 3;
      int kc = p ^ ((r >> 1) & 3);
      cp16(A + (long)(m0 + r) * lda + k0 + kc * 8, &As[lin2 * 8]);
    }
#pragma unroll
    for (int it = 0; it < 2; ++it) {
      int lin2 = it * 256 + tid;
      int r = lin2 >> 2;
      int p = lin2 & 3;
      int kc = p ^ ((r >> 1) & 3);
      cp16(B + (long)(n0 + r) * ldb + k0 + kc * 8, &Bs[lin2 * 8]);
    }
    __syncthreads();

    short8v af[4], bfr[4];
#pragma unroll
    for (int i = 0; i < 4; ++i)
      af[i] = *(const short8v*)(As + (wm + i * 16 + l15) * 32 + cp * 8);
#pragma unroll
    for (int j = 0; j < 4; ++j)
      bfr[j] = *(const short8v*)(Bs + (wn + j * 16 + l15) * 32 + cp * 8);
#pragma unroll
    for (int i = 0; i < 4; ++i)
#pragma unroll
      for (int j = 0; j < 4; ++j)
        acc[i][j] = __builtin_amdgcn_mfma_f32_16x16x32_bf16(af[i], bfr[j],
                                                            acc[i][j], 0, 0, 0);
    __syncthreads();
  }

  // epilogue: C/D layout col=lane&15, row=quad*4+reg
  if (mode == 1) {
    Cb += (long)z * sCb;
#pragma unroll
    for (int i = 0; i < 4; ++i) {
      int rb = m0 + wm + i * 16 + quad * 4;
#pragma unroll
      for (int j = 0; j < 4; ++j) {
        int col = n0 + wn + j * 16 + l15;
#pragma unroll
        for (int reg = 0; reg < 4; ++reg) {
          float v = acc[i][j][reg];
          v = v > 0.f ? v : (expf(v) - 1.f);
          Cb[(long)(rb + reg) * ldcb + col] = f2bf(v);
        }
      }
    }
  } else if (mode == 2) {
    C += (long)z * sC;
#pragma unroll
    for (int i = 0; i < 4; ++i) {
      int rb = m0 + wm + i * 16 + quad * 4;
#pragma unroll
      for (int j = 0; j < 4; ++j) {
        int col = n0 + wn + j * 16 + l15;
#pragma unroll
        for (int reg = 0; reg < 4; ++reg) C[(long)(rb + reg) * ldc + col] = acc[i][j][reg];
      }
    }
  } else {  // mode 0: transposed bf16 + fused a-vector dot
    float a1v[4], a2v[4];
#pragma unroll
    for (int j = 0; j < 4; ++j) {
      int col = n0 + wn + j * 16 + l15;
      a1v[j] = a_vec[col];
      a2v[j] = a_vec[HID + col];
    }
#pragma unroll
    for (int i = 0; i < 4; ++i) {
      int rb = m0 + wm + i * 16 + quad * 4;
      int bb = rb >> 11;  // 2048 rows per batch
      int ml = rb & 2047;
#pragma unroll
      for (int j = 0; j < 4; ++j) {
        int col = n0 + wn + j * 16 + l15;
        short4v pk;
#pragma unroll
        for (int reg = 0; reg < 4; ++reg) pk[reg] = f2bf(acc[i][j][reg]);
        *(short4v*)(Ct + ((long)bb * HID + col) * NN + ml) = pk;
      }
#pragma unroll
      for (int reg = 0; reg < 4; ++reg) {
        float s1 = 0.f, s2 = 0.f;
#pragma unroll
        for (int j = 0; j < 4; ++j) {
          s1 = fmaf(acc[i][j][reg], a1v[j], s1);
          s2 = fmaf(acc[i][j][reg], a2v[j], s2);
        }
#pragma unroll
        for (int off = 1; off < 16; off <<= 1) {
          s1 += __shfl_xor(s1, off);
          s2 += __shfl_xor(s2, off);
        }
        if (l15 == 0) {
          atomicAdd(Wh1g + rb + reg, s1);
          atomicAdd(Wh2g + rb + reg, s2);
        }
      }
    }
  }
}

// ---------------------------------------------------------------------------
// Row softmax with LeakyReLU + bitmask; register-resident; bf16 out.
// One block (256 thr) per row; each thread owns 8 consecutive j.
// ---------------------------------------------------------------------------
__global__ __launch_bounds__(256) void attn_softmax_kernel(
    const float* __restrict__ Wh1, const float* __restrict__ Wh2,
    const unsigned long long* __restrict__ packed, short* __restrict__ att) {
  int row = blockIdx.x;  // 0 .. B*N-1
  int b = row >> 11;
  const unsigned char* bits = (const unsigned char*)(packed + (long)row * 32);
  const float* wh2b = Wh2 + (long)b * NN;
  const int t = threadIdx.x;
  const int lane = t & 63;
  const int wv = t >> 6;

  unsigned m8 = bits[t];
  float wh1 = Wh1[row];
  float4 wa = ((const float4*)(wh2b + t * 8))[0];
  float4 wb = ((const float4*)(wh2b + t * 8))[1];
  float v[8] = {wa.x, wa.y, wa.z, wa.w, wb.x, wb.y, wb.z, wb.w};

  float lmax = -INFINITY;
#pragma unroll
  for (int k = 0; k < 8; ++k) {
    float s = wh1 + v[k];
    s = s > 0.f ? s : ALPHA * s;
    s = ((m8 >> k) & 1u) ? s : NEGV;
    v[k] = s;
    lmax = fmaxf(lmax, s);
  }

  __shared__ float redm[4], reds[4];
#pragma unroll
  for (int off = 32; off > 0; off >>= 1) lmax = fmaxf(lmax, __shfl_xor(lmax, off));
  if (lane == 0) redm[wv] = lmax;
  __syncthreads();
  float m = fmaxf(fmaxf(redm[0], redm[1]), fmaxf(redm[2], redm[3]));

  float lsum = 0.f;
#pragma unroll
  for (int k = 0; k < 8; ++k) {
    float p = __expf(v[k] - m);  // masked -> exp(NEGV-m) == 0
    v[k] = p;
    lsum += p;
  }
#pragma unroll
  for (int off = 32; off > 0; off >>= 1) lsum += __shfl_xor(lsum, off);
  if (lane == 0) reds[wv] = lsum;
  __syncthreads();
  float inv = 1.f / (reds[0] + reds[1] + reds[2] + reds[3]);

  short8v o;
#pragma unroll
  for (int k = 0; k < 8; ++k) o[k] = f2bf(v[k] * inv);
  *(short8v*)(att + (long)row * NN + t * 8) = o;
}

// ---------------------------------------------------------------------------
// Final pooling: out[b,c] = (1/N) * sum_n elu(h2[b,n,c])
// ---------------------------------------------------------------------------
__global__ __launch_bounds__(256) void pool_kernel(
    const float* __restrict__ h2, float* __restrict__ out) {
  int b = blockIdx.y;
  int z = blockIdx.z;  // n-chunk of 64
  int c = blockIdx.x * 256 + threadIdx.x;
  float s = 0.f;
  int n0 = z * 64;
  for (int n = n0; n < n0 + 64; ++n) {
    float v = h2[((long)b * NN + n) * HID + c];
    v = v > 0.f ? v : (expf(v) - 1.f);
    s += v;
  }
  atomicAdd(out + b * HID + c, s * (1.0f / NN));
}

// ---------------------------------------------------------------------------
extern "C" void kernel_launch(void* const* d_in, const int* in_sizes, int n_in,
                              void* d_out, int out_size, void* d_ws,
                              size_t ws_size, hipStream_t stream) {
  const int* node_feats = (const int*)d_in[0];       // (B,N)
  const int* adjs = (const int*)d_in[1];             // (B,N,N)
  const float* embed_table = (const float*)d_in[2];  // (15,HID)
  const float* W_heads = (const float*)d_in[3];      // (4,HID,HID)
  const float* a_heads = (const float*)d_in[4];      // (4,2*HID,1)
  const float* W_out = (const float*)d_in[5];        // (4*HID,HID)
  const float* a_out = (const float*)d_in[6];        // (2*HID,1)
  float* out = (float*)d_out;                        // (B,HID)

  const long M = (long)BB * NN;  // 16384

  // workspace layout
  char* p = (char*)d_ws;
  short* x_bf = (short*)p;  p += (size_t)M * HID * 2;                   // 25 MB
  short* Wt_h = (short*)p;  p += (size_t)NHEADS * HID * HID * 2;        // 4.7 MB
  short* Wt_o = (short*)p;  p += (size_t)HID * (NHEADS * HID) * 2;      // 4.7 MB
  short* Wh_t = (short*)p;  p += (size_t)BB * HID * NN * 2;             // 25 MB
  short* att = (short*)p;   p += (size_t)BB * NN * NN * 2;              // 67 MB
  short* hcat = (short*)p;  p += (size_t)M * NHEADS * HID * 2;          // 100 MB
  float* h2 = (float*)p;    p += (size_t)M * HID * 4;                   // 50 MB
  unsigned long long* padj = (unsigned long long*)p;
  p += (size_t)BB * NN * NN / 8;                                        // 4.2 MB
  float* Wh1 = (float*)p;   p += (size_t)M * 4;
  float* Wh2 = (float*)p;   p += (size_t)M * 4;
  if ((size_t)(p - (char*)d_ws) > ws_size) return;

  // 0) weight transposes + adjacency pack + embedding
  transpose_bf16<<<dim3(HID / 32, HID / 32, NHEADS), 256, 0, stream>>>(
      W_heads, Wt_h, HID, HID, (long)HID * HID, (long)HID * HID);
  transpose_bf16<<<dim3((NHEADS * HID) / 32, HID / 32, 1), 256, 0, stream>>>(
      W_out, Wt_o, NHEADS * HID, HID, 0, 0);
  pack_adj_kernel<<<(int)((long)BB * NN * NN / 256), 256, 0, stream>>>(adjs, padj);
  embed_kernel<<<(int)(M * HID / 256), 256, 0, stream>>>(node_feats,
                                                         embed_table, x_bf);

  // 2) per-head GAT layer
  for (int h = 0; h < NHEADS; ++h) {
    zero_kernel<<<(2 * (int)M + 255) / 256, 256, 0, stream>>>(Wh1, 2 * (int)M);
    // Wh_t(bf16,[b][col][row]) + Wh1/Wh2 = x @ W_h  (grid 6*128*1 = 768 %8==0)
    mfma_gemm<<<dim3(HID / 128, M / 128, 1), 256, 0, stream>>>(
        x_bf, Wt_h + (long)h * HID * HID, HID, HID, HID, 0, 0,
        nullptr, 0, 0, nullptr, 0, 0, Wh_t,
        a_heads + (long)h * 2 * HID, Wh1, Wh2, 0);
    attn_softmax_kernel<<<(int)M, 256, 0, stream>>>(Wh1, Wh2, padj, att);
    // hcat[:, h*HID:(h+1)*HID] = elu(att @ Wh)  (grid 6*16*8 = 768 %8==0)
    mfma_gemm<<<dim3(HID / 128, NN / 128, BB), 256, 0, stream>>>(
        att, Wh_t, NN, NN, NN, (long)NN * NN, (long)HID * NN,
        nullptr, 0, 0, hcat + (long)h * HID, NHEADS * HID,
        (long)NN * NHEADS * HID, nullptr, nullptr, nullptr, nullptr, 1);
  }

  // 3) output GAT layer
  zero_kernel<<<(2 * (int)M + 255) / 256, 256, 0, stream>>>(Wh1, 2 * (int)M);
  mfma_gemm<<<dim3(HID / 128, M / 128, 1), 256, 0, stream>>>(
      hcat, Wt_o, NHEADS * HID, NHEADS * HID, NHEADS * HID, 0, 0,
      nullptr, 0, 0, nullptr, 0, 0, Wh_t, a_out, Wh1, Wh2, 0);
  attn_softmax_kernel<<<(int)M, 256, 0, stream>>>(Wh1, Wh2, padj, att);
  mfma_gemm<<<dim3(HID / 128, NN / 128, BB), 256, 0, stream>>>(
      att, Wh_t, NN, NN, NN, (long)NN * NN, (long)HID * NN,
      h2, HID, (long)NN * HID, nullptr, 0, 0, nullptr, nullptr, nullptr,
      nullptr, 2);

  // 4) mean-pool with ELU
  zero_kernel<<<(BB * HID + 255) / 256, 256, 0, stream>>>(out, BB * HID);
  pool_kernel<<<dim3(HID / 256, BB, NN / 64), 256, 0, stream>>>(h2, out);
}

// Round 4
// 1014.644 us; speedup vs baseline: 7.5326x; 1.0247x over previous
//
#include <hip/hip_runtime.h>
#include <math.h>

#define BB 8
#define NN 2048
#define HID 768
#define NHEADS 4
#define ALPHA 0.2f
#define NEGV -9e15f
#define MTOT (BB * NN)  // 16384

using short4v = __attribute__((ext_vector_type(4))) short;
using short8v = __attribute__((ext_vector_type(8))) short;
using f32x4 = __attribute__((ext_vector_type(4))) float;

__device__ __forceinline__ short f2bf(float f) {
  union { float f; unsigned u; } x;
  x.f = f;
  unsigned r = x.u + 0x7fffu + ((x.u >> 16) & 1u);
  return (short)(r >> 16);
}

__device__ __forceinline__ void cp16(const void* g, void* l) {
  __builtin_amdgcn_global_load_lds(
      (const __attribute__((address_space(1))) unsigned int*)g,
      (__attribute__((address_space(3))) unsigned int*)l, 16, 0, 0);
}

// ---------------------------------------------------------------------------
__global__ __launch_bounds__(256) void embed_kernel(
    const int* __restrict__ nf, const float* __restrict__ table,
    short* __restrict__ x) {
  long idx = (long)blockIdx.x * 256 + threadIdx.x;
  int col = (int)(idx % HID);
  long node = idx / HID;
  x[idx] = f2bf(table[(long)nf[node] * HID + col]);
}

__global__ __launch_bounds__(256) void pack_adj_kernel(
    const int* __restrict__ adj, unsigned long long* __restrict__ packed) {
  long idx = (long)blockIdx.x * 256 + threadIdx.x;
  unsigned long long m = __ballot(adj[idx] > 0);
  if ((threadIdx.x & 63) == 0) packed[idx >> 6] = m;
}

__global__ __launch_bounds__(256) void transpose_bf16(
    const float* __restrict__ W, short* __restrict__ Wt, int K, int N,
    long sIn, long sOut) {
  __shared__ float t[32][33];
  W += (long)blockIdx.z * sIn;
  Wt += (long)blockIdx.z * sOut;
  int k0 = blockIdx.x * 32, n0 = blockIdx.y * 32;
  int tx = threadIdx.x & 31, ty = threadIdx.x >> 5;
#pragma unroll
  for (int i = 0; i < 32; i += 8) t[ty + i][tx] = W[(long)(k0 + ty + i) * N + n0 + tx];
  __syncthreads();
#pragma unroll
  for (int i = 0; i < 32; i += 8)
    Wt[(long)(n0 + ty + i) * K + k0 + tx] = f2bf(t[tx][ty + i]);
}

__global__ __launch_bounds__(256) void zero_kernel(float* __restrict__ p, int n) {
  int i = blockIdx.x * 256 + threadIdx.x;
  if (i < n) p[i] = 0.f;
}

// ---------------------------------------------------------------------------
// bf16 MFMA GEMM, 128x128 tile, BK=32, XCD swizzle.
// mode 0: multi-head epilogue — Ct bf16 [head][bb][colh][row] + fused a-dot
//         (a_vec[head*2H + colh], atomic into Wh1/Wh2[head][row])
// mode 1: Cb bf16 ELU, z = hh*8+b: Cb += b*sCb + hh*HID (column shift)
// mode 2: C fp32, z stride sC
// ---------------------------------------------------------------------------
__global__ __launch_bounds__(256) void mfma_gemm(
    const short* __restrict__ A, const short* __restrict__ B,
    int K, int lda, int ldb, long sA, long sB,
    float* __restrict__ C, int ldc, long sC,
    short* __restrict__ Cb, int ldcb, long sCb,
    short* __restrict__ Ct,
    const float* __restrict__ a_vec, float* __restrict__ Wh1g,
    float* __restrict__ Wh2g, int mode) {
  __shared__ short As[128 * 32];
  __shared__ short Bs[128 * 32];

  const int gx = gridDim.x, gy = gridDim.y;
  int lin = blockIdx.x + gx * (blockIdx.y + gy * blockIdx.z);
  const int per = (gx * gy * gridDim.z) >> 3;
  int work = (lin & 7) * per + (lin >> 3);
  const int bx = work % gx;
  int tmp = work / gx;
  const int by = tmp % gy;
  const int z = tmp / gy;

  A += (long)z * sA;
  B += (long)z * sB;

  const int tid = threadIdx.x;
  const int m0 = by * 128;
  const int n0 = bx * 128;

  const int lane = tid & 63;
  const int wid = tid >> 6;
  const int wm = (wid & 1) * 64;
  const int wn = (wid >> 1) * 64;
  const int l15 = lane & 15;
  const int quad = lane >> 4;
  const int cp = quad ^ ((l15 >> 1) & 3);

  f32x4 acc[4][4];
#pragma unroll
  for (int i = 0; i < 4; ++i)
#pragma unroll
    for (int j = 0; j < 4; ++j) acc[i][j] = (f32x4){0.f, 0.f, 0.f, 0.f};

  for (int k0 = 0; k0 < K; k0 += 32) {
#pragma unroll
    for (int it = 0; it < 2; ++it) {
      int lin2 = it * 256 + tid;
      int r = lin2 >> 2;
      int p = lin2 & 3;
      int kc = p ^ ((r >> 1) & 3);
      cp16(A + (long)(m0 + r) * lda + k0 + kc * 8, &As[lin2 * 8]);
    }
#pragma unroll
    for (int it = 0; it < 2; ++it) {
      int lin2 = it * 256 + tid;
      int r = lin2 >> 2;
      int p = lin2 & 3;
      int kc = p ^ ((r >> 1) & 3);
      cp16(B + (long)(n0 + r) * ldb + k0 + kc * 8, &Bs[lin2 * 8]);
    }
    __syncthreads();

    short8v af[4], bfr[4];
#pragma unroll
    for (int i = 0; i < 4; ++i)
      af[i] = *(const short8v*)(As + (wm + i * 16 + l15) * 32 + cp * 8);
#pragma unroll
    for (int j = 0; j < 4; ++j)
      bfr[j] = *(const short8v*)(Bs + (wn + j * 16 + l15) * 32 + cp * 8);
#pragma unroll
    for (int i = 0; i < 4; ++i)
#pragma unroll
      for (int j = 0; j < 4; ++j)
        acc[i][j] = __builtin_amdgcn_mfma_f32_16x16x32_bf16(af[i], bfr[j],
                                                            acc[i][j], 0, 0, 0);
    __syncthreads();
  }

  if (mode == 1) {
    Cb += (long)(z & 7) * sCb + (long)(z >> 3) * HID;
#pragma unroll
    for (int i = 0; i < 4; ++i) {
      int rb = m0 + wm + i * 16 + quad * 4;
#pragma unroll
      for (int j = 0; j < 4; ++j) {
        int col = n0 + wn + j * 16 + l15;
#pragma unroll
        for (int reg = 0; reg < 4; ++reg) {
          float v = acc[i][j][reg];
          v = v > 0.f ? v : (__expf(v) - 1.f);
          Cb[(long)(rb + reg) * ldcb + col] = f2bf(v);
        }
      }
    }
  } else if (mode == 2) {
    C += (long)z * sC;
#pragma unroll
    for (int i = 0; i < 4; ++i) {
      int rb = m0 + wm + i * 16 + quad * 4;
#pragma unroll
      for (int j = 0; j < 4; ++j) {
        int col = n0 + wn + j * 16 + l15;
#pragma unroll
        for (int reg = 0; reg < 4; ++reg) C[(long)(rb + reg) * ldc + col] = acc[i][j][reg];
      }
    }
  } else {  // mode 0
    int headj[4], colhj[4];
    float a1v[4], a2v[4];
#pragma unroll
    for (int j = 0; j < 4; ++j) {
      int col = n0 + wn + j * 16 + l15;
      int hd = col / HID;  // head boundaries align with 128-tiles
      headj[j] = hd;
      colhj[j] = col - hd * HID;
      a1v[j] = a_vec[hd * 2 * HID + colhj[j]];
      a2v[j] = a_vec[hd * 2 * HID + HID + colhj[j]];
    }
#pragma unroll
    for (int i = 0; i < 4; ++i) {
      int rb = m0 + wm + i * 16 + quad * 4;
      int bb = rb >> 11;
      int ml = rb & 2047;
#pragma unroll
      for (int j = 0; j < 4; ++j) {
        short4v pk;
#pragma unroll
        for (int reg = 0; reg < 4; ++reg) pk[reg] = f2bf(acc[i][j][reg]);
        *(short4v*)(Ct + (((long)headj[j] * BB + bb) * HID + colhj[j]) * NN + ml) = pk;
      }
#pragma unroll
      for (int reg = 0; reg < 4; ++reg) {
        float s1 = 0.f, s2 = 0.f;
#pragma unroll
        for (int j = 0; j < 4; ++j) {
          s1 = fmaf(acc[i][j][reg], a1v[j], s1);
          s2 = fmaf(acc[i][j][reg], a2v[j], s2);
        }
#pragma unroll
        for (int off = 1; off < 16; off <<= 1) {
          s1 += __shfl_xor(s1, off);
          s2 += __shfl_xor(s2, off);
        }
        if (l15 == 0) {  // head is wave-uniform (64 cols within one head span)
          long base = (long)headj[0] * MTOT + rb + reg;
          atomicAdd(Wh1g + base, s1);
          atomicAdd(Wh2g + base, s2);
        }
      }
    }
  }
}

// ---------------------------------------------------------------------------
// Row softmax, nh heads per launch; grid = nh*16384.
// Wh1/Wh2 indexed [head][16384]; att indexed [hh][16384][NN].
// ---------------------------------------------------------------------------
__global__ __launch_bounds__(256) void attn_softmax_kernel(
    const float* __restrict__ Wh1, const float* __restrict__ Wh2,
    const unsigned long long* __restrict__ packed, short* __restrict__ att,
    int head_base) {
  int row = blockIdx.x;
  int hh = row >> 14;
  int rowm = row & 16383;
  int b = rowm >> 11;
  int h = head_base + hh;
  const unsigned char* bits = (const unsigned char*)(packed + (long)rowm * 32);
  const float* wh2b = Wh2 + (long)h * MTOT + b * NN;
  const int t = threadIdx.x;
  const int lane = t & 63;
  const int wv = t >> 6;

  unsigned m8 = bits[t];
  float wh1 = Wh1[(long)h * MTOT + rowm];
  float4 wa = ((const float4*)(wh2b + t * 8))[0];
  float4 wb = ((const float4*)(wh2b + t * 8))[1];
  float v[8] = {wa.x, wa.y, wa.z, wa.w, wb.x, wb.y, wb.z, wb.w};

  float lmax = -INFINITY;
#pragma unroll
  for (int k = 0; k < 8; ++k) {
    float s = wh1 + v[k];
    s = s > 0.f ? s : ALPHA * s;
    s = ((m8 >> k) & 1u) ? s : NEGV;
    v[k] = s;
    lmax = fmaxf(lmax, s);
  }

  __shared__ float redm[4], reds[4];
#pragma unroll
  for (int off = 32; off > 0; off >>= 1) lmax = fmaxf(lmax, __shfl_xor(lmax, off));
  if (lane == 0) redm[wv] = lmax;
  __syncthreads();
  float m = fmaxf(fmaxf(redm[0], redm[1]), fmaxf(redm[2], redm[3]));

  float lsum = 0.f;
#pragma unroll
  for (int k = 0; k < 8; ++k) {
    float p = __expf(v[k] - m);
    v[k] = p;
    lsum += p;
  }
#pragma unroll
  for (int off = 32; off > 0; off >>= 1) lsum += __shfl_xor(lsum, off);
  if (lane == 0) reds[wv] = lsum;
  __syncthreads();
  float inv = 1.f / (reds[0] + reds[1] + reds[2] + reds[3]);

  short8v o;
#pragma unroll
  for (int k = 0; k < 8; ++k) o[k] = f2bf(v[k] * inv);
  *(short8v*)(att + (long)row * NN + t * 8) = o;
}

// ---------------------------------------------------------------------------
__global__ __launch_bounds__(256) void pool_kernel(
    const float* __restrict__ h2, float* __restrict__ out) {
  int b = blockIdx.y;
  int z = blockIdx.z;
  int c = blockIdx.x * 256 + threadIdx.x;
  float s = 0.f;
  int n0 = z * 64;
  for (int n = n0; n < n0 + 64; ++n) {
    float v = h2[((long)b * NN + n) * HID + c];
    v = v > 0.f ? v : (__expf(v) - 1.f);
    s += v;
  }
  atomicAdd(out + b * HID + c, s * (1.0f / NN));
}

// ---------------------------------------------------------------------------
extern "C" void kernel_launch(void* const* d_in, const int* in_sizes, int n_in,
                              void* d_out, int out_size, void* d_ws,
                              size_t ws_size, hipStream_t stream) {
  const int* node_feats = (const int*)d_in[0];
  const int* adjs = (const int*)d_in[1];
  const float* embed_table = (const float*)d_in[2];
  const float* W_heads = (const float*)d_in[3];
  const float* a_heads = (const float*)d_in[4];
  const float* W_out = (const float*)d_in[5];
  const float* a_out = (const float*)d_in[6];
  float* out = (float*)d_out;

  // workspace layout (~423 MB)
  char* p = (char*)d_ws;
  short* x_bf = (short*)p;  p += (size_t)MTOT * HID * 2;                 // 25 MB
  short* Wt_h = (short*)p;  p += (size_t)NHEADS * HID * HID * 2;         // 4.7 MB
  short* Wt_o = (short*)p;  p += (size_t)HID * (NHEADS * HID) * 2;       // 4.7 MB
  short* Wh_t = (short*)p;  p += (size_t)NHEADS * BB * HID * NN * 2;     // 100 MB
  short* att2 = (short*)p;  p += (size_t)2 * BB * NN * NN * 2;           // 134 MB
  short* hcat = (short*)p;  p += (size_t)MTOT * NHEADS * HID * 2;        // 100 MB
  float* h2 = (float*)p;    p += (size_t)MTOT * HID * 4;                 // 50 MB
  unsigned long long* padj = (unsigned long long*)p;
  p += (size_t)BB * NN * NN / 8;                                         // 4.2 MB
  float* Wh1 = (float*)p;   p += (size_t)NHEADS * MTOT * 4;              // 256 KB
  float* Wh2 = (float*)p;   p += (size_t)NHEADS * MTOT * 4;              // 256 KB
  if ((size_t)(p - (char*)d_ws) > ws_size) return;

  // 0) setup
  transpose_bf16<<<dim3(HID / 32, HID / 32, NHEADS), 256, 0, stream>>>(
      W_heads, Wt_h, HID, HID, (long)HID * HID, (long)HID * HID);
  transpose_bf16<<<dim3((NHEADS * HID) / 32, HID / 32, 1), 256, 0, stream>>>(
      W_out, Wt_o, NHEADS * HID, HID, 0, 0);
  pack_adj_kernel<<<(int)((long)BB * NN * NN / 256), 256, 0, stream>>>(adjs, padj);
  embed_kernel<<<(int)((long)MTOT * HID / 256), 256, 0, stream>>>(
      node_feats, embed_table, x_bf);
  zero_kernel<<<(2 * NHEADS * MTOT + 255) / 256, 256, 0, stream>>>(
      Wh1, 2 * NHEADS * MTOT);

  // 1) all-head projection: x @ [W0|..|W3] -> Wh_t + Wh1/Wh2   (3072 blocks)
  mfma_gemm<<<dim3(NHEADS * HID / 128, MTOT / 128, 1), 256, 0, stream>>>(
      x_bf, Wt_h, HID, HID, HID, 0, 0, nullptr, 0, 0, nullptr, 0, 0, Wh_t,
      a_heads, Wh1, Wh2, 0);

  // 2) att layer, two heads at a time
  for (int hb = 0; hb < NHEADS; hb += 2) {
    attn_softmax_kernel<<<2 * MTOT, 256, 0, stream>>>(Wh1, Wh2, padj, att2, hb);
    // hcat cols [hb*768, (hb+2)*768) = elu(att @ Wh)   (1536 blocks)
    mfma_gemm<<<dim3(HID / 128, NN / 128, 16), 256, 0, stream>>>(
        att2, Wh_t + (long)hb * BB * HID * NN, NN, NN, NN, (long)NN * NN,
        (long)HID * NN, nullptr, 0, 0, hcat + (long)hb * HID, NHEADS * HID,
        (long)NN * NHEADS * HID, nullptr, nullptr, nullptr, nullptr, 1);
  }

  // 3) output GAT layer
  zero_kernel<<<(MTOT + 255) / 256, 256, 0, stream>>>(Wh1, MTOT);
  zero_kernel<<<(MTOT + 255) / 256, 256, 0, stream>>>(Wh2, MTOT);
  mfma_gemm<<<dim3(HID / 128, MTOT / 128, 1), 256, 0, stream>>>(
      hcat, Wt_o, NHEADS * HID, NHEADS * HID, NHEADS * HID, 0, 0,
      nullptr, 0, 0, nullptr, 0, 0, Wh_t, a_out, Wh1, Wh2, 0);
  attn_softmax_kernel<<<MTOT, 256, 0, stream>>>(Wh1, Wh2, padj, att2, 0);
  mfma_gemm<<<dim3(HID / 128, NN / 128, BB), 256, 0, stream>>>(
      att2, Wh_t, NN, NN, NN, (long)NN * NN, (long)HID * NN,
      h2, HID, (long)NN * HID, nullptr, 0, 0, nullptr, nullptr, nullptr,
      nullptr, 2);

  // 4) mean-pool with ELU
  zero_kernel<<<(BB * HID + 255) / 256, 256, 0, stream>>>(out, BB * HID);
  pool_kernel<<<dim3(HID / 256, BB, NN / 64), 256, 0, stream>>>(h2, out);
}

// Round 5
// 994.302 us; speedup vs baseline: 7.6867x; 1.0205x over previous
//
#include <hip/hip_runtime.h>
#include <math.h>

#define BB 8
#define NN 2048
#define HID 768
#define NHEADS 4
#define ALPHA 0.2f
#define NEGV -9e15f
#define MTOT (BB * NN)  // 16384

using short4v = __attribute__((ext_vector_type(4))) short;
using short8v = __attribute__((ext_vector_type(8))) short;
using f32x4 = __attribute__((ext_vector_type(4))) float;

__device__ __forceinline__ short f2bf(float f) {
  union { float f; unsigned u; } x;
  x.f = f;
  unsigned r = x.u + 0x7fffu + ((x.u >> 16) & 1u);
  return (short)(r >> 16);
}

__device__ __forceinline__ void cp16(const void* g, void* l) {
  __builtin_amdgcn_global_load_lds(
      (const __attribute__((address_space(1))) unsigned int*)g,
      (__attribute__((address_space(3))) unsigned int*)l, 16, 0, 0);
}

// ---------------------------------------------------------------------------
__global__ __launch_bounds__(256) void embed_kernel(
    const int* __restrict__ nf, const float* __restrict__ table,
    short* __restrict__ x) {
  long idx = (long)blockIdx.x * 256 + threadIdx.x;
  int col = (int)(idx % HID);
  long node = idx / HID;
  x[idx] = f2bf(table[(long)nf[node] * HID + col]);
}

__global__ __launch_bounds__(256) void pack_adj_kernel(
    const int* __restrict__ adj, unsigned long long* __restrict__ packed) {
  long idx = (long)blockIdx.x * 256 + threadIdx.x;
  unsigned long long m = __ballot(adj[idx] > 0);
  if ((threadIdx.x & 63) == 0) packed[idx >> 6] = m;
}

__global__ __launch_bounds__(256) void transpose_bf16(
    const float* __restrict__ W, short* __restrict__ Wt, int K, int N,
    long sIn, long sOut) {
  __shared__ float t[32][33];
  W += (long)blockIdx.z * sIn;
  Wt += (long)blockIdx.z * sOut;
  int k0 = blockIdx.x * 32, n0 = blockIdx.y * 32;
  int tx = threadIdx.x & 31, ty = threadIdx.x >> 5;
#pragma unroll
  for (int i = 0; i < 32; i += 8) t[ty + i][tx] = W[(long)(k0 + ty + i) * N + n0 + tx];
  __syncthreads();
#pragma unroll
  for (int i = 0; i < 32; i += 8)
    Wt[(long)(n0 + ty + i) * K + k0 + tx] = f2bf(t[tx][ty + i]);
}

__global__ __launch_bounds__(256) void zero_kernel(float* __restrict__ p, int n) {
  int i = blockIdx.x * 256 + threadIdx.x;
  if (i < n) p[i] = 0.f;
}

// ---------------------------------------------------------------------------
// bf16 MFMA GEMM, 128x128 tile, BK=32, XCD swizzle, LDS-repacked epilogues.
// mode 0: multi-head — Ct bf16 [head][bb][colh][row] coalesced via LDS +
//         fused a-dot (atomic Wh1/Wh2[head][row])
// mode 1: Cb bf16 ELU (coalesced via LDS); z = hh*8+b -> col shift hh*HID
// mode 3: fused ELU + mean-pool: atomicAdd out[z*HID + col]
// ---------------------------------------------------------------------------
__global__ __launch_bounds__(256) void mfma_gemm(
    const short* __restrict__ A, const short* __restrict__ B,
    int K, int lda, int ldb, long sA, long sB,
    float* __restrict__ Cf, int ldc,
    short* __restrict__ Cb, int ldcb, long sCb,
    short* __restrict__ Ct,
    const float* __restrict__ a_vec, float* __restrict__ Wh1g,
    float* __restrict__ Wh2g, int mode) {
  __shared__ short smem[8704];  // As(4096) + Bs(4096) staged; reused as ctile
  short* As = smem;
  short* Bs = smem + 4096;

  const int gx = gridDim.x, gy = gridDim.y;
  int lin = blockIdx.x + gx * (blockIdx.y + gy * blockIdx.z);
  const int per = (gx * gy * gridDim.z) >> 3;
  int work = (lin & 7) * per + (lin >> 3);
  const int bx = work % gx;
  int tmp = work / gx;
  const int by = tmp % gy;
  const int z = tmp / gy;

  A += (long)z * sA;
  B += (long)z * sB;

  const int tid = threadIdx.x;
  const int m0 = by * 128;
  const int n0 = bx * 128;

  const int lane = tid & 63;
  const int wid = tid >> 6;
  const int wm = (wid & 1) * 64;
  const int wn = (wid >> 1) * 64;
  const int l15 = lane & 15;
  const int quad = lane >> 4;
  const int cp = quad ^ ((l15 >> 1) & 3);

  f32x4 acc[4][4];
#pragma unroll
  for (int i = 0; i < 4; ++i)
#pragma unroll
    for (int j = 0; j < 4; ++j) acc[i][j] = (f32x4){0.f, 0.f, 0.f, 0.f};

  for (int k0 = 0; k0 < K; k0 += 32) {
#pragma unroll
    for (int it = 0; it < 2; ++it) {
      int lin2 = it * 256 + tid;
      int r = lin2 >> 2;
      int p = lin2 & 3;
      int kc = p ^ ((r >> 1) & 3);
      cp16(A + (long)(m0 + r) * lda + k0 + kc * 8, &As[lin2 * 8]);
    }
#pragma unroll
    for (int it = 0; it < 2; ++it) {
      int lin2 = it * 256 + tid;
      int r = lin2 >> 2;
      int p = lin2 & 3;
      int kc = p ^ ((r >> 1) & 3);
      cp16(B + (long)(n0 + r) * ldb + k0 + kc * 8, &Bs[lin2 * 8]);
    }
    __syncthreads();

    short8v af[4], bfr[4];
#pragma unroll
    for (int i = 0; i < 4; ++i)
      af[i] = *(const short8v*)(As + (wm + i * 16 + l15) * 32 + cp * 8);
#pragma unroll
    for (int j = 0; j < 4; ++j)
      bfr[j] = *(const short8v*)(Bs + (wn + j * 16 + l15) * 32 + cp * 8);
#pragma unroll
    for (int i = 0; i < 4; ++i)
#pragma unroll
      for (int j = 0; j < 4; ++j)
        acc[i][j] = __builtin_amdgcn_mfma_f32_16x16x32_bf16(af[i], bfr[j],
                                                            acc[i][j], 0, 0, 0);
    __syncthreads();
  }

  // ---- epilogues (C/D layout: col=lane&15 group, row=quad*4+reg) ----
  if (mode == 1) {
    // ELU -> bf16, coalesced via LDS row-major half-tiles (stride 132)
    Cb += (long)(z & 7) * sCb + (long)(z >> 3) * HID;
#pragma unroll
    for (int p = 0; p < 2; ++p) {
      if (wm == p * 64) {
#pragma unroll
        for (int i = 0; i < 4; ++i) {
          int row_l = i * 16 + quad * 4;
#pragma unroll
          for (int j = 0; j < 4; ++j) {
            int col = wn + j * 16 + l15;
#pragma unroll
            for (int reg = 0; reg < 4; ++reg) {
              float v = acc[i][j][reg];
              v = v > 0.f ? v : (__expf(v) - 1.f);
              smem[(row_l + reg) * 132 + col] = f2bf(v);
            }
          }
        }
      }
      __syncthreads();
#pragma unroll
      for (int it = 0; it < 8; ++it) {
        int idx = it * 256 + tid;
        int row_l = idx >> 5;
        int c4 = idx & 31;
        short4v ld = *(const short4v*)(smem + row_l * 132 + c4 * 4);
        *(short4v*)(Cb + (long)(m0 + p * 64 + row_l) * ldcb + n0 + c4 * 4) = ld;
      }
      __syncthreads();
    }
  } else if (mode == 3) {
    // fused ELU + mean-pool: partial col sums -> atomicAdd out[z*HID+col]
#pragma unroll
    for (int j = 0; j < 4; ++j) {
      int col = n0 + wn + j * 16 + l15;
      float s = 0.f;
#pragma unroll
      for (int i = 0; i < 4; ++i)
#pragma unroll
        for (int reg = 0; reg < 4; ++reg) {
          float v = acc[i][j][reg];
          s += v > 0.f ? v : (__expf(v) - 1.f);
        }
      s += __shfl_xor(s, 16);
      s += __shfl_xor(s, 32);
      if (quad == 0) atomicAdd(Cf + (long)z * HID + col, s * (1.0f / NN));
    }
  } else {  // mode 0: a-dot + transposed Ct via LDS [col][row] (stride 136)
    float a1v[4], a2v[4];
    int head0;
    {
      int col0 = n0 + wn;
      head0 = col0 / HID;
#pragma unroll
      for (int j = 0; j < 4; ++j) {
        int colh = col0 + j * 16 + l15 - head0 * HID;
        a1v[j] = a_vec[head0 * 2 * HID + colh];
        a2v[j] = a_vec[head0 * 2 * HID + HID + colh];
      }
    }
#pragma unroll
    for (int i = 0; i < 4; ++i) {
      int rb = m0 + wm + i * 16 + quad * 4;
#pragma unroll
      for (int reg = 0; reg < 4; ++reg) {
        float s1 = 0.f, s2 = 0.f;
#pragma unroll
        for (int j = 0; j < 4; ++j) {
          s1 = fmaf(acc[i][j][reg], a1v[j], s1);
          s2 = fmaf(acc[i][j][reg], a2v[j], s2);
        }
#pragma unroll
        for (int off = 1; off < 16; off <<= 1) {
          s1 += __shfl_xor(s1, off);
          s2 += __shfl_xor(s2, off);
        }
        if (l15 == 0) {
          long base = (long)head0 * MTOT + rb + reg;
          atomicAdd(Wh1g + base, s1);
          atomicAdd(Wh2g + base, s2);
        }
      }
    }
    const int bb = m0 >> 11;  // 128-row tile lies within one batch
    const int ml0 = m0 & 2047;
#pragma unroll
    for (int p = 0; p < 2; ++p) {
      if (wn == p * 64) {
#pragma unroll
        for (int j = 0; j < 4; ++j) {
          int col_l = j * 16 + l15;  // 0..63 within half
#pragma unroll
          for (int i = 0; i < 4; ++i) {
            int row_l = wm + i * 16 + quad * 4;
            short4v pk;
#pragma unroll
            for (int reg = 0; reg < 4; ++reg) pk[reg] = f2bf(acc[i][j][reg]);
            *(short4v*)(smem + col_l * 136 + row_l) = pk;
          }
        }
      }
      __syncthreads();
#pragma unroll
      for (int it = 0; it < 4; ++it) {
        int idx = it * 256 + tid;
        int col_l = idx >> 4;
        int ch = idx & 15;
        short8v ld = *(const short8v*)(smem + col_l * 136 + ch * 8);
        int col_g = n0 + p * 64 + col_l;
        int hd = col_g / HID;
        int colh = col_g - hd * HID;
        *(short8v*)(Ct + (((long)hd * BB + bb) * HID + colh) * NN + ml0 + ch * 8) = ld;
      }
      __syncthreads();
    }
  }
}

// ---------------------------------------------------------------------------
// Row softmax, nh heads per launch; grid = nh*16384.
// ---------------------------------------------------------------------------
__global__ __launch_bounds__(256) void attn_softmax_kernel(
    const float* __restrict__ Wh1, const float* __restrict__ Wh2,
    const unsigned long long* __restrict__ packed, short* __restrict__ att,
    int head_base) {
  int row = blockIdx.x;
  int hh = row >> 14;
  int rowm = row & 16383;
  int b = rowm >> 11;
  int h = head_base + hh;
  const unsigned char* bits = (const unsigned char*)(packed + (long)rowm * 32);
  const float* wh2b = Wh2 + (long)h * MTOT + b * NN;
  const int t = threadIdx.x;
  const int lane = t & 63;
  const int wv = t >> 6;

  unsigned m8 = bits[t];
  float wh1 = Wh1[(long)h * MTOT + rowm];
  float4 wa = ((const float4*)(wh2b + t * 8))[0];
  float4 wb = ((const float4*)(wh2b + t * 8))[1];
  float v[8] = {wa.x, wa.y, wa.z, wa.w, wb.x, wb.y, wb.z, wb.w};

  float lmax = -INFINITY;
#pragma unroll
  for (int k = 0; k < 8; ++k) {
    float s = wh1 + v[k];
    s = s > 0.f ? s : ALPHA * s;
    s = ((m8 >> k) & 1u) ? s : NEGV;
    v[k] = s;
    lmax = fmaxf(lmax, s);
  }

  __shared__ float redm[4], reds[4];
#pragma unroll
  for (int off = 32; off > 0; off >>= 1) lmax = fmaxf(lmax, __shfl_xor(lmax, off));
  if (lane == 0) redm[wv] = lmax;
  __syncthreads();
  float m = fmaxf(fmaxf(redm[0], redm[1]), fmaxf(redm[2], redm[3]));

  float lsum = 0.f;
#pragma unroll
  for (int k = 0; k < 8; ++k) {
    float p = __expf(v[k] - m);
    v[k] = p;
    lsum += p;
  }
#pragma unroll
  for (int off = 32; off > 0; off >>= 1) lsum += __shfl_xor(lsum, off);
  if (lane == 0) reds[wv] = lsum;
  __syncthreads();
  float inv = 1.f / (reds[0] + reds[1] + reds[2] + reds[3]);

  short8v o;
#pragma unroll
  for (int k = 0; k < 8; ++k) o[k] = f2bf(v[k] * inv);
  *(short8v*)(att + (long)row * NN + t * 8) = o;
}

// ---------------------------------------------------------------------------
extern "C" void kernel_launch(void* const* d_in, const int* in_sizes, int n_in,
                              void* d_out, int out_size, void* d_ws,
                              size_t ws_size, hipStream_t stream) {
  const int* node_feats = (const int*)d_in[0];
  const int* adjs = (const int*)d_in[1];
  const float* embed_table = (const float*)d_in[2];
  const float* W_heads = (const float*)d_in[3];
  const float* a_heads = (const float*)d_in[4];
  const float* W_out = (const float*)d_in[5];
  const float* a_out = (const float*)d_in[6];
  float* out = (float*)d_out;

  // workspace layout (~373 MB)
  char* p = (char*)d_ws;
  short* x_bf = (short*)p;  p += (size_t)MTOT * HID * 2;                 // 25 MB
  short* Wt_h = (short*)p;  p += (size_t)NHEADS * HID * HID * 2;         // 4.7 MB
  short* Wt_o = (short*)p;  p += (size_t)HID * (NHEADS * HID) * 2;       // 4.7 MB
  short* Wh_t = (short*)p;  p += (size_t)NHEADS * BB * HID * NN * 2;     // 100 MB
  short* att2 = (short*)p;  p += (size_t)2 * BB * NN * NN * 2;           // 134 MB
  short* hcat = (short*)p;  p += (size_t)MTOT * NHEADS * HID * 2;        // 100 MB
  unsigned long long* padj = (unsigned long long*)p;
  p += (size_t)BB * NN * NN / 8;                                         // 4.2 MB
  float* Wh1 = (float*)p;   p += (size_t)NHEADS * MTOT * 4;
  float* Wh2 = (float*)p;   p += (size_t)NHEADS * MTOT * 4;
  if ((size_t)(p - (char*)d_ws) > ws_size) return;

  // 0) setup
  transpose_bf16<<<dim3(HID / 32, HID / 32, NHEADS), 256, 0, stream>>>(
      W_heads, Wt_h, HID, HID, (long)HID * HID, (long)HID * HID);
  transpose_bf16<<<dim3((NHEADS * HID) / 32, HID / 32, 1), 256, 0, stream>>>(
      W_out, Wt_o, NHEADS * HID, HID, 0, 0);
  pack_adj_kernel<<<(int)((long)BB * NN * NN / 256), 256, 0, stream>>>(adjs, padj);
  embed_kernel<<<(int)((long)MTOT * HID / 256), 256, 0, stream>>>(
      node_feats, embed_table, x_bf);
  zero_kernel<<<(2 * NHEADS * MTOT + 255) / 256, 256, 0, stream>>>(
      Wh1, 2 * NHEADS * MTOT);

  // 1) all-head projection: x @ [W0|..|W3] -> Wh_t + Wh1/Wh2  (3072 blocks)
  mfma_gemm<<<dim3(NHEADS * HID / 128, MTOT / 128, 1), 256, 0, stream>>>(
      x_bf, Wt_h, HID, HID, HID, 0, 0, nullptr, 0, nullptr, 0, 0, Wh_t,
      a_heads, Wh1, Wh2, 0);

  // 2) att layer, two heads at a time
  for (int hb = 0; hb < NHEADS; hb += 2) {
    attn_softmax_kernel<<<2 * MTOT, 256, 0, stream>>>(Wh1, Wh2, padj, att2, hb);
    mfma_gemm<<<dim3(HID / 128, NN / 128, 16), 256, 0, stream>>>(
        att2, Wh_t + (long)hb * BB * HID * NN, NN, NN, NN, (long)NN * NN,
        (long)HID * NN, nullptr, 0, hcat + (long)hb * HID, NHEADS * HID,
        (long)NN * NHEADS * HID, nullptr, nullptr, nullptr, nullptr, 1);
  }

  // 3) output GAT layer
  zero_kernel<<<(MTOT + 255) / 256, 256, 0, stream>>>(Wh1, MTOT);
  zero_kernel<<<(MTOT + 255) / 256, 256, 0, stream>>>(Wh2, MTOT);
  mfma_gemm<<<dim3(HID / 128, MTOT / 128, 1), 256, 0, stream>>>(
      hcat, Wt_o, NHEADS * HID, NHEADS * HID, NHEADS * HID, 0, 0,
      nullptr, 0, nullptr, 0, 0, Wh_t, a_out, Wh1, Wh2, 0);
  attn_softmax_kernel<<<MTOT, 256, 0, stream>>>(Wh1, Wh2, padj, att2, 0);
  // final att @ Who with fused ELU+mean-pool -> out
  zero_kernel<<<(BB * HID + 255) / 256, 256, 0, stream>>>(out, BB * HID);
  mfma_gemm<<<dim3(HID / 128, NN / 128, BB), 256, 0, stream>>>(
      att2, Wh_t, NN, NN, NN, (long)NN * NN, (long)HID * NN,
      out, 0, nullptr, 0, 0, nullptr, nullptr, nullptr, nullptr, 3);
}